// Round 3
// baseline (407.694 us; speedup 1.0000x reference)
//
#include <hip/hip_runtime.h>
#include <math.h>

// DILATE loss: 0.5*mean(softDTW) + 0.5*sum(E*Omega)/(B*N*N) + MSE
// B=64, N=256, K=1, gamma=0.01.
//
// One wave per batch, lane p owns rows 4p+1..4p+4. SKEW-2 pipeline: lane p
// handles column j = s-2p+1 at step s (forward), j = N-u+2*(63-p) at step u
// (backward). All cross-lane values (R boundary row, x column values) travel
// through 2-step-delayed shuffle pipelines, so ds_permute latency (~120cy) is
// fully hidden behind one step of compute. Backward R slabs prefetched 2 deep.
// Zero barriers, zero LDS on the critical path.
//
// ws: [0, 64*382*64*16 B = 25 MB) R slabs [b][s][p]; then 64*3 doubles.

#define BB 64
#define NN 256
#define PP 64
#define NSTEP (NN + 2 * (PP - 1))  // 382
#define INF_F 100000000.0f
#define ESC 144.26950408889634f   /* (1/gamma) * log2(e) */
#define LSC 0.006931471805599453f /* gamma * ln(2) */

__device__ __forceinline__ float fwd_cell(float a, float b, float c, float ti, float xj) {
  const float m = fminf(a, fminf(b, c));
  const float s = exp2f((m - a) * ESC) + exp2f((m - b) * ESC) + exp2f((m - c) * ESC);
  const float smin = m - LSC * log2f(s);
  const float dx = ti - xj;
  return fmaf(dx, dx, smin);
}

__global__ __launch_bounds__(64) void sdtw_kernel(
    const float* __restrict__ input, const float* __restrict__ target,
    float4* __restrict__ Rws, double* __restrict__ partial) {
  const int b = blockIdx.x;
  const int p = threadIdx.x;
  __shared__ float xs[NN];

  const float4 xv4 = ((const float4*)(input + b * NN))[p];
  const float4 tv4 = ((const float4*)(target + b * NN))[p];
  ((float4*)xs)[p] = xv4;
  const float t0 = tv4.x, t1 = tv4.y, t2 = tv4.z, t3 = tv4.w;
  const float t4 = __shfl_down(t0, 1);  // t for row 4p+5 (lane p+1's top row)
  __syncthreads();

  double msel;
  {
    const float d0 = xv4.x - tv4.x, d1 = xv4.y - tv4.y;
    const float d2 = xv4.z - tv4.z, d3 = xv4.w - tv4.w;
    msel = (double)(d0 * d0) + (double)(d1 * d1) + (double)(d2 * d2) + (double)(d3 * d3);
  }

  float4* __restrict__ Rb = Rws + (size_t)b * NSTEP * PP;

  // ---------------- forward (skew 2) ----------------
  float prev0 = INF_F, prev1 = INF_F, prev2 = INF_F, prev3 = INF_F;
  float cur0 = INF_F, cur1 = INF_F, cur2 = INF_F, cur3 = INF_F;
  float tl = (p == 0) ? 0.0f : INF_F;  // R[4p][j-1]
  float ttop = INF_F;                  // R[4p][j]
  float ttop_s1 = INF_F;               // arrives for use at s+1
  float x_use = xs[0];                 // x[j-1] for this step (lane-uniform init ok)
  float x_s1 = xs[1];                  // for next step
  for (int s = 0; s < NSTEP; ++s) {
    const float xpre = xs[(s + 2 < NN) ? (s + 2) : (NN - 1)];  // lane0 injection for s+2
    const int j = s - 2 * p + 1;
    const bool act = (j >= 1) & (j <= NN);
    if (act) {
      cur0 = fwd_cell(tl, ttop, prev0, t0, x_use);
      cur1 = fwd_cell(prev0, cur0, prev1, t1, x_use);
      cur2 = fwd_cell(prev1, cur1, prev2, t2, x_use);
      cur3 = fwd_cell(prev2, cur2, prev3, t3, x_use);
      Rb[(size_t)s * PP + p] = make_float4(cur0, cur1, cur2, cur3);
      prev0 = cur0; prev1 = cur1; prev2 = cur2; prev3 = cur3;
    }
    // 2-step-delay pipelines (issue now, consume at s+2)
    const float shN = __shfl_up(cur3, 1);   // lane p-1's cur3(s) = R[4p][j+2]
    const float xsh = __shfl_up(x_use, 1);  // lane p-1's x(s)    = x[(s+2)-2p]
    tl = ttop;
    ttop = ttop_s1;
    ttop_s1 = (p == 0) ? INF_F : shN;
    x_use = x_s1;
    x_s1 = (p == 0) ? xpre : xsh;
  }
  const float r_nn = __shfl(cur3, PP - 1);  // R[N][N]

  __builtin_amdgcn_s_waitcnt(0);  // drain forward stores before backward loads

  // ---------------- backward (skew 2) ----------------
  // E[i][j] = sum over successors of exp((R_s - D_s - R_ij)/g) * E_s; E[N][N]=1.
  float Rr0 = 0.f, Rr1 = 0.f, Rr2 = 0.f, Rr3 = 0.f;  // R[rows][j+1] (own lane, prev step)
  float Er0 = 0.f, Er1 = 0.f, Er2 = 0.f, Er3 = 0.f;  // E[rows][j+1]
  float bR0 = 0.f, bR1 = 0.f, bE0 = 0.f, bE1 = 0.f;  // R/E[4p+5][j], [4p+5][j+1]
  float bR_s1 = 0.f, bE_s1 = 0.f;                    // delay slots
  float xlo = xs[NN - 1];       // x[j-1]
  float xhi = xs[NN - 1];       // x[j] (unused at j==N)
  float xlo_s1 = xs[NN - 2];    // delay slot
  float4 Rc = Rb[(size_t)(NSTEP - 1) * PP + p];      // slab for u=0
  float4 Rc_s1 = Rb[(size_t)(NSTEP - 2) * PP + p];   // slab for u=1
  double tsum = 0.0;

  for (int u = 0; u < NSTEP; ++u) {
    const int sp = NSTEP - 3 - u;                          // slab for u+2
    const float4 Rnew = Rb[(size_t)(sp < 0 ? 0 : sp) * PP + p];
    const float xpre = xs[(NN - 3 - u) >= 0 ? (NN - 3 - u) : 0];  // lane63 injection
    const int j = NN - u + 2 * (PP - 1 - p);
    const bool act = (j >= 1) & (j <= NN);
    float e0 = 0.f, e1 = 0.f, e2 = 0.f, e3 = 0.f;
    if (act) {
      const bool jr = (j < NN);
      const bool pb = (p < PP - 1);
      // k=3 (row 4p+4): successors (i+1,j) via bR0/bE0, (i,j+1), (i+1,j+1) via bR1/bE1
      {
        const float da = t4 - xlo;
        float w = pb ? exp2f((bR0 - da * da - Rc.w) * ESC) * bE0 : 0.0f;
        const float dr = t3 - xhi;
        w += jr ? exp2f((Rr3 - dr * dr - Rc.w) * ESC) * Er3 : 0.0f;
        const float dd = t4 - xhi;
        w += (pb & jr) ? exp2f((bR1 - dd * dd - Rc.w) * ESC) * bE1 : 0.0f;
        e3 = w;
      }
      if ((p == PP - 1) & (u == 0)) e3 = 1.0f;  // seed E[N][N]
      // k=2
      {
        const float da = t3 - xlo;
        float w = exp2f((Rc.w - da * da - Rc.z) * ESC) * e3;
        const float dr = t2 - xhi;
        w += jr ? exp2f((Rr2 - dr * dr - Rc.z) * ESC) * Er2 : 0.0f;
        const float dd = t3 - xhi;
        w += jr ? exp2f((Rr3 - dd * dd - Rc.z) * ESC) * Er3 : 0.0f;
        e2 = w;
      }
      // k=1
      {
        const float da = t2 - xlo;
        float w = exp2f((Rc.z - da * da - Rc.y) * ESC) * e2;
        const float dr = t1 - xhi;
        w += jr ? exp2f((Rr1 - dr * dr - Rc.y) * ESC) * Er1 : 0.0f;
        const float dd = t2 - xhi;
        w += jr ? exp2f((Rr2 - dd * dd - Rc.y) * ESC) * Er2 : 0.0f;
        e1 = w;
      }
      // k=0 (row 4p+1)
      {
        const float da = t1 - xlo;
        float w = exp2f((Rc.y - da * da - Rc.x) * ESC) * e1;
        const float dr = t0 - xhi;
        w += jr ? exp2f((Rr0 - dr * dr - Rc.x) * ESC) * Er0 : 0.0f;
        const float dd = t1 - xhi;
        w += jr ? exp2f((Rr1 - dd * dd - Rc.x) * ESC) * Er1 : 0.0f;
        e0 = w;
      }
      const float f0 = (float)(4 * p + 1 - j);
      const float f1 = f0 + 1.0f, f2 = f0 + 2.0f, f3 = f0 + 3.0f;
      tsum += (double)(e0 * f0 * f0) + (double)(e1 * f1 * f1) +
              (double)(e2 * f2 * f2) + (double)(e3 * f3 * f3);
      Rr0 = Rc.x; Rr1 = Rc.y; Rr2 = Rc.z; Rr3 = Rc.w;
      Er0 = e0; Er1 = e1; Er2 = e2; Er3 = e3;
    }
    // 2-step-delay pipelines (all lanes execute; consumed values always from
    // active sources by construction)
    const float sR  = __shfl_down(Rc.x, 1);
    const float sE  = __shfl_down(e0, 1);
    const float sxl = __shfl_down(xlo, 1);
    bR1 = bR0; bE1 = bE0;
    bR0 = bR_s1; bE0 = bE_s1;
    bR_s1 = sR; bE_s1 = sE;
    xhi = xlo;
    xlo = xlo_s1;
    xlo_s1 = (p == PP - 1) ? xpre : sxl;
    Rc = Rc_s1;
    Rc_s1 = Rnew;
  }

  // ---------------- wave reductions ----------------
  for (int off = 32; off > 0; off >>= 1) {
    tsum += __shfl_xor(tsum, off);
    msel += __shfl_xor(msel, off);
  }
  if (p == 0) {
    partial[b * 3 + 0] = (double)r_nn;
    partial[b * 3 + 1] = tsum;
    partial[b * 3 + 2] = msel;
  }
}

__global__ __launch_bounds__(64) void finalize_kernel(const double* __restrict__ partial,
                                                      float* __restrict__ out) {
  const int t = threadIdx.x;  // one lane per batch
  double sd = partial[t * 3 + 0];
  double ts = partial[t * 3 + 1];
  double ms = partial[t * 3 + 2];
  for (int off = 32; off > 0; off >>= 1) {
    sd += __shfl_xor(sd, off);
    ts += __shfl_xor(ts, off);
    ms += __shfl_xor(ms, off);
  }
  if (t == 0) {
    const double loss_shape = sd / (double)BB;
    const double loss_temporal = ts / ((double)BB * NN * NN);
    const double mse = ms / ((double)BB * NN);
    out[0] = (float)(0.5 * loss_shape + 0.5 * loss_temporal + mse);
  }
}

extern "C" void kernel_launch(void* const* d_in, const int* in_sizes, int n_in,
                              void* d_out, int out_size, void* d_ws, size_t ws_size,
                              hipStream_t stream) {
  const float* input = (const float*)d_in[0];
  const float* target = (const float*)d_in[1];
  float4* Rws = (float4*)d_ws;
  double* partial = (double*)((char*)d_ws + (size_t)BB * NSTEP * PP * sizeof(float4));
  float* out = (float*)d_out;

  sdtw_kernel<<<BB, PP, 0, stream>>>(input, target, Rws, partial);
  finalize_kernel<<<1, 64, 0, stream>>>(partial, out);
}